// Round 3
// baseline (551.883 us; speedup 1.0000x reference)
//
#include <hip/hip_runtime.h>

// LNNRegression: fused 6-wave-specialized pipelined scan.
//   w0: x DMA (global_load_lds, depth-4 ring, pre-barrier vmcnt(2)) + gate
//   w1: pre_f/pre_s (lag 3) + tau reduce (lag 4)
//   w2: fast&slow LTC recurrence (lag 5)
//   w3: fusion outputs 0-31 (lag 6, inner-split + shfl combine)
//   w4: fusion outputs 32-63 (lag 6)
//   w5: attention + online softmax (lag 7)
// Max 32 weight floats/lane -> every role fits ~50 VGPRs (round-2 theory:
// role0's 80+ live values overflowed to AGPRs, paying accvgpr copies).
// Depth-4 LDS rings; ONE raw barrier (lgkmcnt only) per step, vmcnt counted.

#define T_  512
#define D_  31
#define NIT 519   // 512 + 7 pipeline lag

__device__ __forceinline__ float fexp2(float x){ return __builtin_amdgcn_exp2f(x); }
__device__ __forceinline__ float frcp (float x){ return __builtin_amdgcn_rcpf(x); }
__device__ __forceinline__ float fast_tanh(float x){
    float e = fexp2(x * 2.8853900817779268f);
    return 1.0f - 2.0f * frcp(1.0f + e);
}
__device__ __forceinline__ float fast_sigmoid(float x){
    return frcp(1.0f + fexp2(x * -1.4426950408889634f));
}
#define L2E 1.4426950408889634f

#define BAR() do { asm volatile("s_waitcnt lgkmcnt(0)" ::: "memory"); \
                   __builtin_amdgcn_s_barrier();                      \
                   asm volatile("" ::: "memory"); } while (0)

#define DOT32(res, warr, base4)                                         \
    do { float a0_=0.f,a1_=0.f,a2_=0.f,a3_=0.f;                         \
        _Pragma("unroll")                                               \
        for (int c_ = 0; c_ < 8; ++c_) {                                \
            float4 q_ = (base4)[c_];                                    \
            a0_ += (warr)[4*c_+0]*q_.x; a1_ += (warr)[4*c_+1]*q_.y;     \
            a2_ += (warr)[4*c_+2]*q_.z; a3_ += (warr)[4*c_+3]*q_.w; }   \
        res = (a0_+a1_)+(a2_+a3_); } while (0)

__launch_bounds__(384, 6)
__global__ void lnn_fused(
    const float* __restrict__ X,
    const float* __restrict__ fg_w1, const float* __restrict__ fg_b1,
    const float* __restrict__ fg_w2, const float* __restrict__ fg_b2,
    const float* __restrict__ fwin,  const float* __restrict__ fbin,
    const float* __restrict__ fwrec,
    const float* __restrict__ swin,  const float* __restrict__ sbin,
    const float* __restrict__ swrec,
    const float* __restrict__ fu_w,  const float* __restrict__ fu_b,
    const float* __restrict__ at_w1, const float* __restrict__ at_b1,
    const float* __restrict__ at_w2, const float* __restrict__ at_b2,
    const float* __restrict__ d_w1,  const float* __restrict__ d_b1,
    const float* __restrict__ d_w2,  const float* __restrict__ d_b2,
    const float* __restrict__ o_w1,  const float* __restrict__ o_b1,
    const float* __restrict__ o_w2,  const float* __restrict__ o_b2,
    const float* __restrict__ o_w3,  const float* __restrict__ o_b3,
    const float* __restrict__ i_w1,  const float* __restrict__ i_b1,
    const float* __restrict__ i_w2,  const float* __restrict__ i_b2,
    float* __restrict__ out, int B)
{
    const int b    = blockIdx.x;
    const int tx   = threadIdx.x;
    const int wid  = tx / 64;
    const int lane = tx & 63;

    __shared__ float x_sh  [4][32];   // DMA ring (31 + zero pad)
    __shared__ float h1_sh [4][32];   // gate hidden
    __shared__ float pre_sh[4][64];   // pre_f | pre_s (bias included)
    __shared__ float tau_sh[4];       // 1/tau_fast scalar
    __shared__ float h_sh  [4][64];   // fast h | slow h
    __shared__ float ltc_sh[4][64];
    __shared__ float ctx_sh[64];

    if (tx < 64) h_sh[3][tx] = 0.0f;            // h_{-1} = 0 (t=0 reads slot 3)
    if (tx < 4)  x_sh[tx][31] = 0.0f;           // pads

    if (wid == 0) {
        // ============ w0: x DMA + FlashFloodGate hidden ============
        float w[32];
        const int u = lane & 31;
        const float* g = fg_w1 + u*62;
        if (lane < 32) {
            #pragma unroll
            for (int j = 0; j < 31; ++j) w[j] = g[j] + g[31+j];   // (A+B) row
        } else {
            #pragma unroll
            for (int j = 0; j < 31; ++j) w[j] = g[31+j];          // B row -> y
        }
        w[31] = 0.0f;
        const float sA = (lane < 32) ? fg_b1[u] : 0.0f;
        const float* xsrc = X + (size_t)b * T_ * D_ + lane;
        float y_prev = 0.0f;
        asm volatile("s_waitcnt vmcnt(0)" ::: "memory");   // weights drained

        for (int i = 0; i < NIT; ++i) {
            // DMA(i-3) landed before the barrier -> all waves may read x(i-3)
            asm volatile("s_waitcnt vmcnt(2)" ::: "memory");
            BAR();
            if (lane < D_)
                __builtin_amdgcn_global_load_lds(
                    (const __attribute__((address_space(1))) unsigned int*)xsrc,
                    (__attribute__((address_space(3))) unsigned int*)(&x_sh[i & 3][0]),
                    4, 0, 0);
            if (i < T_ - 1) xsrc += D_;

            const int t0 = i - 3;
            if (t0 >= 0 && t0 < T_) {
                const float4* xq4 = (const float4*)(&x_sh[t0 & 3][0]);
                float ag; DOT32(ag, w, xq4);
                float yt   = __shfl_xor(ag, 32);        // lanes<32 get y_t
                float ycur = (t0 == 0) ? yt : y_prev;   // dx_0 = 0
                y_prev = yt;
                float h1 = fast_tanh(ag - ycur + sA);
                if (lane < 32) h1_sh[t0 & 3][lane] = h1;
            }
        }
        asm volatile("s_waitcnt vmcnt(0)" ::: "memory");   // drain before endpgm
    } else if (wid == 1) {
        // ============ w1: pre_f/pre_s (lag 3) + tau (lag 4) ============
        float w[32];
        const int u = lane & 31;
        const float* wr = (lane < 32) ? (fwin + u*31) : (swin + u*31);
        #pragma unroll
        for (int j = 0; j < 31; ++j) w[j] = wr[j];
        w[31] = 0.0f;
        const float sB = (lane < 32) ? fbin[u] : sbin[u];
        const float g2 = fg_w2[u];
        const float b2 = fg_b2[0];
        asm volatile("s_waitcnt vmcnt(0)" ::: "memory");

        for (int i = 0; i < NIT; ++i) {
            BAR();
            const int t0 = i - 3;
            if (t0 >= 0 && t0 < T_) {
                const float4* xq4 = (const float4*)(&x_sh[t0 & 3][0]);
                float ap; DOT32(ap, w, xq4);
                pre_sh[t0 & 3][lane] = ap + sB;
            }
            const int t1 = i - 4;
            if (t1 >= 0 && t1 < T_) {
                float v = h1_sh[t1 & 3][u] * g2;
                v += __shfl_xor(v, 1);  v += __shfl_xor(v, 2);
                v += __shfl_xor(v, 4);  v += __shfl_xor(v, 8);
                v += __shfl_xor(v, 16);
                float cs = fast_sigmoid(v + b2);
                if (lane == 0) tau_sh[t1 & 3] = frcp(10.0f - 9.99f * cs);
            }
        }
    } else if (wid == 2) {
        // ============ w2: LTC recurrence (lag 5) ============
        float w[32];
        const int u = lane & 31;
        const float* wr = (lane < 32) ? (fwrec + u*32) : (swrec + u*32);
        #pragma unroll
        for (int j = 0; j < 32; ++j) w[j] = wr[j];
        float h_st = 0.0f;
        asm volatile("s_waitcnt vmcnt(0)" ::: "memory");

        for (int i = 0; i < NIT; ++i) {
            BAR();
            const int t = i - 5;
            if (t >= 0 && t < T_) {
                const int s = t & 3;
                float rt = (lane < 32) ? tau_sh[s] : 0.2f;
                const float4* hp = (const float4*)(h_sh[(t + 3) & 3] + (lane & 32));
                float acc; DOT32(acc, w, hp);
                float upd = fast_tanh(acc + pre_sh[s][lane]);
                h_st += (upd - h_st) * rt;
                h_sh[s][lane] = h_st;
            }
        }
    } else if (wid == 3 || wid == 4) {
        // ============ w3/w4: fusion halves (lag 6) ============
        float w[32];
        const int r  = (wid == 3 ? 0 : 32) + (lane & 31);
        const int hb = lane & 32;
        #pragma unroll
        for (int j = 0; j < 32; ++j) w[j] = fu_w[r*64 + hb + j];
        const float sA = fu_b[r];
        asm volatile("s_waitcnt vmcnt(0)" ::: "memory");

        for (int i = 0; i < NIT; ++i) {
            BAR();
            const int t = i - 6;
            if (t >= 0 && t < T_) {
                const int s = t & 3;
                const float4* hp = (const float4*)(h_sh[s] + hb);
                float acc; DOT32(acc, w, hp);
                float ax = __shfl_xor(acc, 32);
                if (lane < 32) ltc_sh[s][r] = fast_tanh(acc + ax + sA);
            }
        }
    } else {
        // ============ w5: attention + online softmax (lag 7) ============
        float w[32];
        const int r  = lane & 31;
        const int hb = lane & 32;
        #pragma unroll
        for (int j = 0; j < 32; ++j) w[j] = at_w1[r*64 + hb + j];
        const float sA = at_b1[r];
        const float sB = at_w2[r];
        const float sC = at_b2[0];
        float m_run = -1.0e30f, s_run = 0.0f, c_run = 0.0f;
        asm volatile("s_waitcnt vmcnt(0)" ::: "memory");

        for (int i = 0; i < NIT; ++i) {
            BAR();
            const int t = i - 7;
            if (t >= 0 && t < T_) {
                const int s = t & 3;
                float lt = ltc_sh[s][lane];
                const float4* lp = (const float4*)(ltc_sh[s] + hb);
                float acc; DOT32(acc, w, lp);
                acc += __shfl_xor(acc, 32);
                float a1 = fast_tanh(acc + sA);
                float v  = a1 * sB;
                v += __shfl_xor(v, 1);  v += __shfl_xor(v, 2);
                v += __shfl_xor(v, 4);  v += __shfl_xor(v, 8);
                v += __shfl_xor(v, 16);
                float logit = v + sC;
                float mn = fmaxf(m_run, logit);
                float e1 = fexp2((m_run - mn) * L2E);
                float p  = fexp2((logit - mn) * L2E);
                s_run = s_run * e1 + p;
                c_run = c_run * e1 + p * lt;
                m_run = mn;
            }
        }
        ctx_sh[lane] = c_run * frcp(s_run);
    }

    // ---------------- epilogue: heads ----------------
    BAR();

    if (wid == 0) {
        // depths head: Linear(64->64)+relu, Linear(64->5)
        float r1 = d_b1[lane];
        #pragma unroll
        for (int c = 0; c < 16; ++c) {
            float4 cq = ((const float4*)ctx_sh)[c];
            float4 wq = ((const float4*)(d_w1 + lane*64))[c];
            r1 += wq.x*cq.x + wq.y*cq.y + wq.z*cq.z + wq.w*cq.w;
        }
        r1 = fmaxf(r1, 0.0f);
        #pragma unroll
        for (int k = 0; k < 5; ++k) {
            float v = d_w2[k*64 + lane] * r1;
            v += __shfl_xor(v, 1);  v += __shfl_xor(v, 2);
            v += __shfl_xor(v, 4);  v += __shfl_xor(v, 8);
            v += __shfl_xor(v, 16); v += __shfl_xor(v, 32);
            if (lane == 0) out[b*5 + k] = v + d_b2[k];
        }
    } else if (wid == 1) {
        // overflow head: 64->64 relu, 64->32 relu, 32->1 sigmoid
        float r1 = o_b1[lane];
        #pragma unroll
        for (int c = 0; c < 16; ++c) {
            float4 cq = ((const float4*)ctx_sh)[c];
            float4 wq = ((const float4*)(o_w1 + lane*64))[c];
            r1 += wq.x*cq.x + wq.y*cq.y + wq.z*cq.z + wq.w*cq.w;
        }
        r1 = fmaxf(r1, 0.0f);
        const int r  = lane & 31;
        const int hb = lane & 32;
        float acc = 0.0f;
        #pragma unroll
        for (int j = 0; j < 32; ++j) {
            float rj = __shfl(r1, hb + j);
            acc += o_w2[r*64 + hb + j] * rj;
        }
        acc += __shfl_xor(acc, 32);
        float r2 = fmaxf(acc + o_b2[r], 0.0f);
        float v  = o_w3[r] * r2;
        v += __shfl_xor(v, 1);  v += __shfl_xor(v, 2);
        v += __shfl_xor(v, 4);  v += __shfl_xor(v, 8);
        v += __shfl_xor(v, 16);
        if (lane == 0) out[5*B + b] = fast_sigmoid(v + o_b3[0]);
    } else if (wid == 2) {
        // intensity head: 64->32 relu, 32->1 sigmoid
        const int r  = lane & 31;
        const int hb = lane & 32;
        float acc = 0.0f;
        #pragma unroll
        for (int c = 0; c < 8; ++c) {
            float4 cq = ((const float4*)(ctx_sh + hb))[c];
            float4 wq = ((const float4*)(i_w1 + r*64 + hb))[c];
            acc += wq.x*cq.x + wq.y*cq.y + wq.z*cq.z + wq.w*cq.w;
        }
        acc += __shfl_xor(acc, 32);
        float r1 = fmaxf(acc + i_b1[r], 0.0f);
        float v  = i_w2[r] * r1;
        v += __shfl_xor(v, 1);  v += __shfl_xor(v, 2);
        v += __shfl_xor(v, 4);  v += __shfl_xor(v, 8);
        v += __shfl_xor(v, 16);
        if (lane == 0) out[6*B + b] = fast_sigmoid(v + i_b2[0]);
    }
}

extern "C" void kernel_launch(void* const* d_in, const int* in_sizes, int n_in,
                              void* d_out, int out_size, void* d_ws, size_t ws_size,
                              hipStream_t stream) {
    (void)n_in; (void)out_size; (void)d_ws; (void)ws_size;
    const float* X     = (const float*)d_in[0];
    const float* fg_w1 = (const float*)d_in[1];
    const float* fg_b1 = (const float*)d_in[2];
    const float* fg_w2 = (const float*)d_in[3];
    const float* fg_b2 = (const float*)d_in[4];
    const float* fwin  = (const float*)d_in[5];
    const float* fbin  = (const float*)d_in[6];
    const float* fwrec = (const float*)d_in[7];
    const float* swin  = (const float*)d_in[8];
    const float* sbin  = (const float*)d_in[9];
    const float* swrec = (const float*)d_in[10];
    const float* fu_w  = (const float*)d_in[11];
    const float* fu_b  = (const float*)d_in[12];
    const float* at_w1 = (const float*)d_in[13];
    const float* at_b1 = (const float*)d_in[14];
    const float* at_w2 = (const float*)d_in[15];
    const float* at_b2 = (const float*)d_in[16];
    const float* d_w1  = (const float*)d_in[17];
    const float* d_b1  = (const float*)d_in[18];
    const float* d_w2  = (const float*)d_in[19];
    const float* d_b2  = (const float*)d_in[20];
    const float* o_w1  = (const float*)d_in[21];
    const float* o_b1  = (const float*)d_in[22];
    const float* o_w2  = (const float*)d_in[23];
    const float* o_b2  = (const float*)d_in[24];
    const float* o_w3  = (const float*)d_in[25];
    const float* o_b3  = (const float*)d_in[26];
    const float* i_w1  = (const float*)d_in[27];
    const float* i_b1  = (const float*)d_in[28];
    const float* i_w2  = (const float*)d_in[29];
    const float* i_b2  = (const float*)d_in[30];
    float* out = (float*)d_out;

    const int B = in_sizes[0] / (T_ * D_);
    dim3 grid(B), block(384);
    hipLaunchKernelGGL(lnn_fused, grid, block, 0, stream,
        X, fg_w1, fg_b1, fg_w2, fg_b2, fwin, fbin, fwrec, swin, sbin, swrec,
        fu_w, fu_b, at_w1, at_b1, at_w2, at_b2, d_w1, d_b1, d_w2, d_b2,
        o_w1, o_b1, o_w2, o_b2, o_w3, o_b3, i_w1, i_b1, i_w2, i_b2, out, B);
}